// Round 12
// baseline (58.295 us; speedup 1.0000x reference)
//
#include <hip/hip_runtime.h>

typedef _Float16 h2 __attribute__((ext_vector_type(2)));

// Problem constants (fixed by harness shapes)
static constexpr int B2   = 2;
static constexpr int C    = 256;
static constexpr int H    = 48;
static constexpr int W    = 64;
static constexpr int NLVL = 4;
static constexpr int D1   = 32;
static constexpr int P    = H * W;          // 3072
static constexpr int CHO  = NLVL * 8 * D1;  // 1024 output channels

// Workspace layout (BYTES):
//   fp16 f1cl : [B][P][C]                      @ 0
//   fp8  pyr  : levels 0..3 channels-last      @ F1_BYTES
//   fp16 out_tmp : [B][P][CHO]                 @ OT_OFF
static constexpr size_t F1_BYTES = (size_t)B2 * P * C * 2;
static constexpr size_t PL0 = 0;
static constexpr size_t PL1 = PL0 + (size_t)B2 * 48 * 64 * C;
static constexpr size_t PL2 = PL1 + (size_t)B2 * 24 * 32 * C;
static constexpr size_t PL3 = PL2 + (size_t)B2 * 12 * 16 * C;
static constexpr size_t PYR_BYTES = PL3 + (size_t)B2 * 6 * 8 * C;
static constexpr size_t OT_OFF    = F1_BYTES + PYR_BYTES;
static constexpr size_t OT_BYTES  = (size_t)B2 * P * CHO * 2;
static constexpr size_t WS_NEEDED = OT_OFF + OT_BYTES;  // ~17.8 MB

#if defined(__has_builtin)
#if __has_builtin(__builtin_amdgcn_cvt_scalef32_pk_f16_fp8)
#define HAS_HW_FP8_DEC 1
#endif
#if __has_builtin(__builtin_amdgcn_cvt_pk_fp8_f32)
#define HAS_HW_FP8_ENC 1
#endif
#endif

#ifdef HAS_HW_FP8_DEC
static constexpr float WSC = 1.0f;    // hw decode produces true value
#else
static constexpr float WSC = 256.0f;  // bit-trick decode yields value * 2^-8
#endif

__device__ __forceinline__ h2 u2h(unsigned u) {
  union { unsigned u; h2 h; } c; c.u = u; return c.h;
}
__device__ __forceinline__ unsigned h2u(h2 h) {
  union { unsigned u; h2 h; } c; c.h = h; return c.u;
}
__device__ __forceinline__ h2 habs2(h2 x) { return u2h(h2u(x) & 0x7FFF7FFFu); }

// ---- fp8 e4m3 encode: one dword (4 channels) from 4 f32 ----
#ifdef HAS_HW_FP8_ENC
__device__ __forceinline__ unsigned packdw(float a, float b, float c, float d) {
  int v = __builtin_amdgcn_cvt_pk_fp8_f32(a, b, 0, false);
  v = __builtin_amdgcn_cvt_pk_fp8_f32(c, d, v, true);
  return (unsigned)v;
}
#else
// software e4m3 (RNE, flush |v|<2^-6, clamp 448) — cold path only
__device__ __forceinline__ unsigned f2e4m3(float f) {
  const unsigned b = __float_as_uint(f);
  const unsigned s = (b >> 24) & 0x80u;
  const float a = fabsf(f);
  if (a < 0.015625f) return s;
  if (a >= 448.f) return s | 0x7Eu;
  const unsigned m   = (b >> 20) & 0x7u;
  const unsigned rem = b & 0xFFFFFu;
  const unsigned e32 = (b >> 23) & 0xFFu;
  unsigned v = ((e32 - 120u) << 3) | m;
  if (rem > 0x80000u || (rem == 0x80000u && (v & 1u))) ++v;
  if (v > 0x7Eu) v = 0x7Eu;
  return s | v;
}
__device__ __forceinline__ unsigned packdw(float a, float b, float c, float d) {
  return f2e4m3(a) | (f2e4m3(b) << 8) | (f2e4m3(c) << 16) | (f2e4m3(d) << 24);
}
#endif

#ifndef HAS_HW_FP8_DEC
// 4 fp8 (one dword) -> two h2, each = true_value * 2^-8 (re-bias folded into
// WSC). Exact for normals AND denormals under the 2^-8 scheme.
__device__ __forceinline__ void fp8x4_to_h2x2(unsigned x, h2& lo, h2& hi) {
  const unsigned lo16 = ((x & 0x7Fu) << 7) | ((x & 0x80u) << 8) |
                        ((x & 0x7F00u) << 15) | ((x & 0x8000u) << 16);
  const unsigned y = x >> 16;
  const unsigned hi16 = ((y & 0x7Fu) << 7) | ((y & 0x80u) << 8) |
                        ((y & 0x7F00u) << 15) | ((y & 0x8000u) << 16);
  lo = u2h(lo16); hi = u2h(hi16);
}
#endif

#define PACK8(v, i0) make_uint2(packdw(v[(i0)], v[(i0)+1], v[(i0)+2], v[(i0)+3]), \
                                packdw(v[(i0)+4], v[(i0)+5], v[(i0)+6], v[(i0)+7]))

// ---------------------------------------------------------------------------
// A: fused prep. grid (4, 6, 32), block 256.
//   z <  16: fmap2 -> channels-last fp8 level0 + pooled levels 1..3.
//   z >= 16: fmap1 -> channels-last fp16.
// ---------------------------------------------------------------------------
__global__ __launch_bounds__(256) void k_prep(
    const float* __restrict__ f1, const float* __restrict__ f2,
    char* __restrict__ ws) {
  __shared__ float s0[32][8][16];  // [c][y][x]
  __shared__ float s1[32][4][8];
  __shared__ float s2[32][2][4];
  const int x0 = blockIdx.x * 16;
  const int y0 = blockIdx.y * 8;
  const int z  = blockIdx.z;
  const bool isf1 = (z >= 16);
  const int zb = z & 15;
  const int b  = zb >> 3;
  const int c0 = (zb & 7) * 32;
  const int t  = threadIdx.x;
  const int tx = t & 15, ty = (t >> 4) & 3, tc = t >> 6;

  const float* src = (isf1 ? f1 : f2) + ((size_t)b * C + c0) * P;
#pragma unroll
  for (int k = 0; k < 8; ++k) {
    const int c = tc + 4 * k;
#pragma unroll
    for (int j = 0; j < 2; ++j) {
      const int y = ty + 4 * j;
      s0[c][y][tx] = src[(size_t)c * P + (size_t)(y0 + y) * W + (x0 + tx)];
    }
  }
  __syncthreads();

  char* pyr = ws + F1_BYTES;

  // phase 2: write level0 (fp8) or f1cl (fp16); others compute level1
  if (t < 128) {
    const int y = t >> 4, x = t & 15;
    float v[32];
#pragma unroll
    for (int e = 0; e < 32; ++e) v[e] = s0[e][y][x];
    if (isf1) {
      union { uint4 q[4]; h2 hh[16]; } u;
#pragma unroll
      for (int e = 0; e < 16; ++e) {
        u.hh[e].x = (_Float16)v[2 * e];
        u.hh[e].y = (_Float16)v[2 * e + 1];
      }
      char* dst = ws + (((size_t)b * P + (size_t)(y0 + y) * W + (x0 + x)) * C + c0) * 2;
#pragma unroll
      for (int q = 0; q < 4; ++q) reinterpret_cast<uint4*>(dst)[q] = u.q[q];
    } else {
      char* dst = pyr + PL0 + ((size_t)b * P + (size_t)(y0 + y) * W + (x0 + x)) * C + c0;
      reinterpret_cast<uint2*>(dst)[0] = PACK8(v, 0);
      reinterpret_cast<uint2*>(dst)[1] = PACK8(v, 8);
      reinterpret_cast<uint2*>(dst)[2] = PACK8(v, 16);
      reinterpret_cast<uint2*>(dst)[3] = PACK8(v, 24);
    }
  } else if (!isf1) {
    const int u0 = t - 128;
#pragma unroll
    for (int k = 0; k < 8; ++k) {
      const int idx = u0 + 128 * k;
      const int c = idx >> 5, r = idx & 31, y = r >> 3, x = r & 7;
      s1[c][y][x] = 0.25f * (s0[c][2 * y][2 * x] + s0[c][2 * y][2 * x + 1] +
                             s0[c][2 * y + 1][2 * x] + s0[c][2 * y + 1][2 * x + 1]);
    }
  }
  if (isf1) return;
  __syncthreads();

  // phase 3: write level1 (fp8); compute level2
  if (t < 32) {
    const int y = t >> 3, x = t & 7;
    float v[32];
#pragma unroll
    for (int e = 0; e < 32; ++e) v[e] = s1[e][y][x];
    char* dst = pyr + PL1 +
                ((size_t)b * (24 * 32) + (size_t)(y0 / 2 + y) * 32 + (x0 / 2 + x)) * C + c0;
    reinterpret_cast<uint2*>(dst)[0] = PACK8(v, 0);
    reinterpret_cast<uint2*>(dst)[1] = PACK8(v, 8);
    reinterpret_cast<uint2*>(dst)[2] = PACK8(v, 16);
    reinterpret_cast<uint2*>(dst)[3] = PACK8(v, 24);
  } else if (t >= 64 && t < 192) {
    const int u0 = t - 64;
#pragma unroll
    for (int k = 0; k < 2; ++k) {
      const int idx = u0 + 128 * k;
      const int c = idx >> 3, r = idx & 7, y = r >> 2, x = r & 3;
      s2[c][y][x] = 0.25f * (s1[c][2 * y][2 * x] + s1[c][2 * y][2 * x + 1] +
                             s1[c][2 * y + 1][2 * x] + s1[c][2 * y + 1][2 * x + 1]);
    }
  }
  __syncthreads();

  // phase 4: write level2; compute+write level3
  if (t < 8) {
    const int y = t >> 2, x = t & 3;
    float v[32];
#pragma unroll
    for (int e = 0; e < 32; ++e) v[e] = s2[e][y][x];
    char* dst = pyr + PL2 +
                ((size_t)b * (12 * 16) + (size_t)(y0 / 4 + y) * 16 + (x0 / 4 + x)) * C + c0;
    reinterpret_cast<uint2*>(dst)[0] = PACK8(v, 0);
    reinterpret_cast<uint2*>(dst)[1] = PACK8(v, 8);
    reinterpret_cast<uint2*>(dst)[2] = PACK8(v, 16);
    reinterpret_cast<uint2*>(dst)[3] = PACK8(v, 24);
  } else if (t >= 8 && t < 10) {
    const int x = t - 8;
    float v[32];
#pragma unroll
    for (int e = 0; e < 32; ++e)
      v[e] = 0.25f * (s2[e][0][2 * x] + s2[e][0][2 * x + 1] +
                      s2[e][1][2 * x] + s2[e][1][2 * x + 1]);
    char* dst = pyr + PL3 +
                ((size_t)b * (6 * 8) + (size_t)(y0 / 8) * 8 + (x0 / 8 + x)) * C + c0;
    reinterpret_cast<uint2*>(dst)[0] = PACK8(v, 0);
    reinterpret_cast<uint2*>(dst)[1] = PACK8(v, 8);
    reinterpret_cast<uint2*>(dst)[2] = PACK8(v, 16);
    reinterpret_cast<uint2*>(dst)[3] = PACK8(v, 24);
  }
}

// ---------------------------------------------------------------------------
// C: main sampler (R9 structure — best measured). One block per (b,pix),
// XCD-chunk-swizzled, 4 waves. 16 lanes per sample; lane owns 16 fp8
// channels (one uint4 per corner). Depth-2 sample pairing; (256,4) bound
// avoids the (256,8) scratch spill. This sits at the random-gather L2
// throughput wall (~46 us for 805 MB of 256B-granule reads).
// ---------------------------------------------------------------------------
template <int STAGED>
__global__ __launch_bounds__(256, 4) void k_sample(
    const _Float16* __restrict__ f1cl, const char* __restrict__ pyr,
    const float* __restrict__ coords, float* __restrict__ dstf,
    _Float16* __restrict__ dsth) {
  __shared__ uint4 s_off[128];
  __shared__ uint4 s_w[128];
  __shared__ float s_out[128 * 9];
  const int bid0 = blockIdx.x;
  const int bid  = (bid0 & 7) * 768 + (bid0 >> 3);  // XCD chunk swizzle
  const int b    = (bid >= P) ? 1 : 0;
  const int pix  = bid - b * P;
  const int t    = threadIdx.x;

  if (t < 128) {
    const int lvl = t >> 5, d = t & 31;
    const float cx = coords[(((size_t)(b * 2 + 0) * NLVL + lvl) * D1 + d) * P + pix];
    const float cy = coords[(((size_t)(b * 2 + 1) * NLVL + lvl) * D1 + d) * P + pix];
    const int Hi = H >> lvl, Wi = W >> lvl;
    const float sc = 1.0f / (float)(1 << lvl);
    const float xf = (cx + 0.5f) * sc - 0.5f;
    const float yf = (cy + 0.5f) * sc - 0.5f;
    const float x0f = floorf(xf), y0f = floorf(yf);
    const int x0 = (int)x0f, y0 = (int)y0f;
    const int x1 = x0 + 1, y1 = y0 + 1;
    const float fx = xf - x0f, fy = yf - y0f;
    const float vx0 = (x0 >= 0 && x0 < Wi) ? -WSC : 0.f;  // negated weights
    const float vx1 = (x1 >= 0 && x1 < Wi) ? -WSC : 0.f;
    const float vy0 = (y0 >= 0 && y0 < Hi) ? 1.f : 0.f;
    const float vy1 = (y1 >= 0 && y1 < Hi) ? 1.f : 0.f;
    const int x0c = min(max(x0, 0), Wi - 1), x1c = min(max(x1, 0), Wi - 1);
    const int y0c = min(max(y0, 0), Hi - 1), y1c = min(max(y1, 0), Hi - 1);
    h2 p00, p10, p01, p11;
    p00.x = p00.y = (_Float16)((1.f - fx) * (1.f - fy) * vx0 * vy0);
    p10.x = p10.y = (_Float16)(fx * (1.f - fy) * vx1 * vy0);
    p01.x = p01.y = (_Float16)((1.f - fx) * fy * vx0 * vy1);
    p11.x = p11.y = (_Float16)(fx * fy * vx1 * vy1);
    s_w[t] = make_uint4(h2u(p00), h2u(p10), h2u(p01), h2u(p11));
    // pyr-relative byte offsets, level+batch base folded in
    const unsigned npx = (unsigned)(Hi * Wi);
    const unsigned lbase =
        (unsigned)((lvl == 0) ? PL0 : (lvl == 1) ? PL1 : (lvl == 2) ? PL2 : PL3) +
        (unsigned)b * npx * C;
    s_off[t] = make_uint4(lbase + (unsigned)(y0c * Wi + x0c) * C,
                          lbase + (unsigned)(y0c * Wi + x1c) * C,
                          lbase + (unsigned)(y1c * Wi + x0c) * C,
                          lbase + (unsigned)(y1c * Wi + x1c) * C);
  }

  const int lane = t & 63;
  const int wave = t >> 6;
  const int q    = lane >> 4;   // quarter-wave = sample slot
  const int li   = lane & 15;   // lane within sample
  const unsigned chb = (unsigned)li * 16u;  // fp8 byte offset of lane's 16 ch

  // f1 fragment: 16 channels fp16 (32 B)
  h2 f1h[8];
  {
    const uint4* fp = reinterpret_cast<const uint4*>(
        reinterpret_cast<const char*>(f1cl) + ((size_t)b * P + pix) * (C * 2) + li * 32);
    const uint4 fa = fp[0], fb = fp[1];
    f1h[0] = u2h(fa.x); f1h[1] = u2h(fa.y); f1h[2] = u2h(fa.z); f1h[3] = u2h(fa.w);
    f1h[4] = u2h(fb.x); f1h[5] = u2h(fb.y); f1h[6] = u2h(fb.z); f1h[7] = u2h(fb.w);
  }

  __syncthreads();

#ifdef HAS_HW_FP8_DEC
#define DECFMA(v, wu)                                                          \
  {                                                                            \
    const h2 w = u2h(wu);                                                      \
    acc[0] += w * __builtin_amdgcn_cvt_scalef32_pk_f16_fp8((v).x, 1.0f, false);\
    acc[1] += w * __builtin_amdgcn_cvt_scalef32_pk_f16_fp8((v).x, 1.0f, true); \
    acc[2] += w * __builtin_amdgcn_cvt_scalef32_pk_f16_fp8((v).y, 1.0f, false);\
    acc[3] += w * __builtin_amdgcn_cvt_scalef32_pk_f16_fp8((v).y, 1.0f, true); \
    acc[4] += w * __builtin_amdgcn_cvt_scalef32_pk_f16_fp8((v).z, 1.0f, false);\
    acc[5] += w * __builtin_amdgcn_cvt_scalef32_pk_f16_fp8((v).z, 1.0f, true); \
    acc[6] += w * __builtin_amdgcn_cvt_scalef32_pk_f16_fp8((v).w, 1.0f, false);\
    acc[7] += w * __builtin_amdgcn_cvt_scalef32_pk_f16_fp8((v).w, 1.0f, true); \
  }
#else
#define DECFMA(v, wu)                                                          \
  {                                                                            \
    const h2 w = u2h(wu);                                                      \
    h2 lo, hi;                                                                 \
    fp8x4_to_h2x2((v).x, lo, hi); acc[0] += w * lo; acc[1] += w * hi;          \
    fp8x4_to_h2x2((v).y, lo, hi); acc[2] += w * lo; acc[3] += w * hi;          \
    fp8x4_to_h2x2((v).z, lo, hi); acc[4] += w * lo; acc[5] += w * hi;          \
    fp8x4_to_h2x2((v).w, lo, hi); acc[6] += w * lo; acc[7] += w * hi;          \
  }
#endif

#define REDUCE_STORE(sidx)                                                     \
  {                                                                            \
    const h2 s01 = habs2(acc[0]) + habs2(acc[1]);                              \
    const h2 s23 = habs2(acc[2]) + habs2(acc[3]);                              \
    const h2 s45 = habs2(acc[4]) + habs2(acc[5]);                              \
    const h2 s67 = habs2(acc[6]) + habs2(acc[7]);                              \
    const h2 s   = (s01 + s23) + (s45 + s67);                                  \
    float a = (float)s.x + (float)s.y;                                         \
    a += __shfl_xor(a, 1);                                                     \
    if ((li & 1) == 0) s_out[(sidx) * 9 + (li >> 1)] = a * (1.0f / 32.0f);     \
  }

#pragma unroll
  for (int ip = 0; ip < 4; ++ip) {
    const int sA = (2 * ip) * 16 + wave * 4 + q;
    const int sB = sA + 16;
    const uint4 oA = s_off[sA], wA = s_w[sA];
    const uint4 oB = s_off[sB], wB = s_w[sB];
    // issue all 8 corner loads (A then B) before any compute
    const uint4 a0 = *reinterpret_cast<const uint4*>(pyr + (oA.x + chb));
    const uint4 a1 = *reinterpret_cast<const uint4*>(pyr + (oA.y + chb));
    const uint4 a2 = *reinterpret_cast<const uint4*>(pyr + (oA.z + chb));
    const uint4 a3 = *reinterpret_cast<const uint4*>(pyr + (oA.w + chb));
    const uint4 b0 = *reinterpret_cast<const uint4*>(pyr + (oB.x + chb));
    const uint4 b1 = *reinterpret_cast<const uint4*>(pyr + (oB.y + chb));
    const uint4 b2 = *reinterpret_cast<const uint4*>(pyr + (oB.z + chb));
    const uint4 b3 = *reinterpret_cast<const uint4*>(pyr + (oB.w + chb));
    {
      h2 acc[8];
#pragma unroll
      for (int k = 0; k < 8; ++k) acc[k] = f1h[k];
      DECFMA(a0, wA.x) DECFMA(a1, wA.y) DECFMA(a2, wA.z) DECFMA(a3, wA.w)
      REDUCE_STORE(sA)
    }
    {
      h2 acc[8];
#pragma unroll
      for (int k = 0; k < 8; ++k) acc[k] = f1h[k];
      DECFMA(b0, wB.x) DECFMA(b1, wB.y) DECFMA(b2, wB.z) DECFMA(b3, wB.w)
      REDUCE_STORE(sB)
    }
  }

  __syncthreads();
  if (STAGED) {
    union { unsigned qq[2]; h2 hh[2]; } u;
#pragma unroll
    for (int j = 0; j < 2; ++j) {
      const int c0i = t * 4 + j * 2;
      const int c1i = c0i + 1;
      u.hh[j].x = (_Float16)s_out[((c0i >> 8) * 32 + (c0i & 31)) * 9 + ((c0i >> 5) & 7)];
      u.hh[j].y = (_Float16)s_out[((c1i >> 8) * 32 + (c1i & 31)) * 9 + ((c1i >> 5) & 7)];
    }
    *reinterpret_cast<uint2*>(dsth + ((size_t)b * P + pix) * CHO + t * 4) =
        make_uint2(u.qq[0], u.qq[1]);
  } else {
#pragma unroll
    for (int j = 0; j < 4; ++j) {
      const int ch = t * 4 + j;
      dstf[((size_t)b * CHO + ch) * P + pix] =
          s_out[((ch >> 8) * 32 + (ch & 31)) * 9 + ((ch >> 5) & 7)];
    }
  }
}

// ---------------------------------------------------------------------------
// D: transpose out_tmp fp16 [B][P][CHO] -> out f32 [B][CHO][P].
// ---------------------------------------------------------------------------
__global__ __launch_bounds__(256) void k_out_t(
    const _Float16* __restrict__ ot, float* __restrict__ out) {
  __shared__ float tile[32][33];
  const int b  = blockIdx.z;
  const int p0 = blockIdx.x * 32;
  const int c0 = blockIdx.y * 32;
  const int tx = threadIdx.x, ty = threadIdx.y;
#pragma unroll
  for (int i = 0; i < 32; i += 8)
    tile[ty + i][tx] = (float)ot[((size_t)b * P + p0 + ty + i) * CHO + c0 + tx];
  __syncthreads();
#pragma unroll
  for (int i = 0; i < 32; i += 8)
    out[((size_t)b * CHO + c0 + ty + i) * P + p0 + tx] = tile[tx][ty + i];
}

extern "C" void kernel_launch(void* const* d_in, const int* in_sizes, int n_in,
                              void* d_out, int out_size, void* d_ws, size_t ws_size,
                              hipStream_t stream) {
  const float* fmap1  = (const float*)d_in[0];
  const float* fmap2  = (const float*)d_in[1];
  const float* coords = (const float*)d_in[2];
  float* out = (float*)d_out;
  char* ws   = (char*)d_ws;

  k_prep<<<dim3(4, 6, 32), 256, 0, stream>>>(fmap1, fmap2, ws);

  const _Float16* f1cl = (const _Float16*)ws;
  const char* pyr = ws + F1_BYTES;
  if (ws_size >= WS_NEEDED) {
    _Float16* ot = (_Float16*)(ws + OT_OFF);
    k_sample<1><<<B2 * P, 256, 0, stream>>>(f1cl, pyr, coords, out, ot);
    k_out_t<<<dim3(96, 32, 2), dim3(32, 8), 0, stream>>>(ot, out);
  } else {
    k_sample<0><<<B2 * P, 256, 0, stream>>>(f1cl, pyr, coords, out, nullptr);
  }
}

// Round 13
// 57.705 us; speedup vs baseline: 1.0102x; 1.0102x over previous
//
#include <hip/hip_runtime.h>

typedef _Float16 h2 __attribute__((ext_vector_type(2)));

// Problem constants (fixed by harness shapes)
static constexpr int B2   = 2;
static constexpr int C    = 256;
static constexpr int H    = 48;
static constexpr int W    = 64;
static constexpr int NLVL = 4;
static constexpr int D1   = 32;
static constexpr int P    = H * W;          // 3072
static constexpr int CHO  = NLVL * 8 * D1;  // 1024 output channels

// Workspace layout (BYTES):
//   fp16 f1cl : [B][P][C]                      @ 0
//   fp8  pyr  : levels 0..3 channels-last      @ F1_BYTES
//   fp16 out_tmp : [B][P][CHO]                 @ OT_OFF
static constexpr size_t F1_BYTES = (size_t)B2 * P * C * 2;
static constexpr size_t PL0 = 0;
static constexpr size_t PL1 = PL0 + (size_t)B2 * 48 * 64 * C;
static constexpr size_t PL2 = PL1 + (size_t)B2 * 24 * 32 * C;
static constexpr size_t PL3 = PL2 + (size_t)B2 * 12 * 16 * C;
static constexpr size_t PYR_BYTES = PL3 + (size_t)B2 * 6 * 8 * C;
static constexpr size_t OT_OFF    = F1_BYTES + PYR_BYTES;
static constexpr size_t OT_BYTES  = (size_t)B2 * P * CHO * 2;
static constexpr size_t WS_NEEDED = OT_OFF + OT_BYTES;  // ~17.8 MB

#if defined(__has_builtin)
#if __has_builtin(__builtin_amdgcn_cvt_scalef32_pk_f16_fp8)
#define HAS_HW_FP8_DEC 1
#endif
#if __has_builtin(__builtin_amdgcn_cvt_pk_fp8_f32)
#define HAS_HW_FP8_ENC 1
#endif
#endif

#ifdef HAS_HW_FP8_DEC
static constexpr float WSC = 1.0f;    // hw decode produces true value
#else
static constexpr float WSC = 256.0f;  // bit-trick decode yields value * 2^-8
#endif

__device__ __forceinline__ h2 u2h(unsigned u) {
  union { unsigned u; h2 h; } c; c.u = u; return c.h;
}
__device__ __forceinline__ unsigned h2u(h2 h) {
  union { unsigned u; h2 h; } c; c.h = h; return c.u;
}
__device__ __forceinline__ h2 habs2(h2 x) { return u2h(h2u(x) & 0x7FFF7FFFu); }

// ---- fp8 e4m3 encode: one dword (4 channels) from 4 f32 ----
#ifdef HAS_HW_FP8_ENC
__device__ __forceinline__ unsigned packdw(float a, float b, float c, float d) {
  int v = __builtin_amdgcn_cvt_pk_fp8_f32(a, b, 0, false);
  v = __builtin_amdgcn_cvt_pk_fp8_f32(c, d, v, true);
  return (unsigned)v;
}
#else
// software e4m3 (RNE, flush |v|<2^-6, clamp 448) — cold path only
__device__ __forceinline__ unsigned f2e4m3(float f) {
  const unsigned b = __float_as_uint(f);
  const unsigned s = (b >> 24) & 0x80u;
  const float a = fabsf(f);
  if (a < 0.015625f) return s;
  if (a >= 448.f) return s | 0x7Eu;
  const unsigned m   = (b >> 20) & 0x7u;
  const unsigned rem = b & 0xFFFFFu;
  const unsigned e32 = (b >> 23) & 0xFFu;
  unsigned v = ((e32 - 120u) << 3) | m;
  if (rem > 0x80000u || (rem == 0x80000u && (v & 1u))) ++v;
  if (v > 0x7Eu) v = 0x7Eu;
  return s | v;
}
__device__ __forceinline__ unsigned packdw(float a, float b, float c, float d) {
  return f2e4m3(a) | (f2e4m3(b) << 8) | (f2e4m3(c) << 16) | (f2e4m3(d) << 24);
}
#endif

#ifndef HAS_HW_FP8_DEC
// 4 fp8 (one dword) -> two h2, each = true_value * 2^-8 (re-bias folded into
// WSC). Exact for normals AND denormals under the 2^-8 scheme.
__device__ __forceinline__ void fp8x4_to_h2x2(unsigned x, h2& lo, h2& hi) {
  const unsigned lo16 = ((x & 0x7Fu) << 7) | ((x & 0x80u) << 8) |
                        ((x & 0x7F00u) << 15) | ((x & 0x8000u) << 16);
  const unsigned y = x >> 16;
  const unsigned hi16 = ((y & 0x7Fu) << 7) | ((y & 0x80u) << 8) |
                        ((y & 0x7F00u) << 15) | ((y & 0x8000u) << 16);
  lo = u2h(lo16); hi = u2h(hi16);
}
#endif

#define PACK8(v, i0) make_uint2(packdw(v[(i0)], v[(i0)+1], v[(i0)+2], v[(i0)+3]), \
                                packdw(v[(i0)+4], v[(i0)+5], v[(i0)+6], v[(i0)+7]))

// ---------------------------------------------------------------------------
// A: fused prep. grid (4, 6, 32), block 256.
//   z <  16: fmap2 -> channels-last fp8 level0 + pooled levels 1..3.
//   z >= 16: fmap1 -> channels-last fp16.
// ---------------------------------------------------------------------------
__global__ __launch_bounds__(256) void k_prep(
    const float* __restrict__ f1, const float* __restrict__ f2,
    char* __restrict__ ws) {
  __shared__ float s0[32][8][16];  // [c][y][x]
  __shared__ float s1[32][4][8];
  __shared__ float s2[32][2][4];
  const int x0 = blockIdx.x * 16;
  const int y0 = blockIdx.y * 8;
  const int z  = blockIdx.z;
  const bool isf1 = (z >= 16);
  const int zb = z & 15;
  const int b  = zb >> 3;
  const int c0 = (zb & 7) * 32;
  const int t  = threadIdx.x;
  const int tx = t & 15, ty = (t >> 4) & 3, tc = t >> 6;

  const float* src = (isf1 ? f1 : f2) + ((size_t)b * C + c0) * P;
#pragma unroll
  for (int k = 0; k < 8; ++k) {
    const int c = tc + 4 * k;
#pragma unroll
    for (int j = 0; j < 2; ++j) {
      const int y = ty + 4 * j;
      s0[c][y][tx] = src[(size_t)c * P + (size_t)(y0 + y) * W + (x0 + tx)];
    }
  }
  __syncthreads();

  char* pyr = ws + F1_BYTES;

  // phase 2: write level0 (fp8) or f1cl (fp16); others compute level1
  if (t < 128) {
    const int y = t >> 4, x = t & 15;
    float v[32];
#pragma unroll
    for (int e = 0; e < 32; ++e) v[e] = s0[e][y][x];
    if (isf1) {
      union { uint4 q[4]; h2 hh[16]; } u;
#pragma unroll
      for (int e = 0; e < 16; ++e) {
        u.hh[e].x = (_Float16)v[2 * e];
        u.hh[e].y = (_Float16)v[2 * e + 1];
      }
      char* dst = ws + (((size_t)b * P + (size_t)(y0 + y) * W + (x0 + x)) * C + c0) * 2;
#pragma unroll
      for (int q = 0; q < 4; ++q) reinterpret_cast<uint4*>(dst)[q] = u.q[q];
    } else {
      char* dst = pyr + PL0 + ((size_t)b * P + (size_t)(y0 + y) * W + (x0 + x)) * C + c0;
      reinterpret_cast<uint2*>(dst)[0] = PACK8(v, 0);
      reinterpret_cast<uint2*>(dst)[1] = PACK8(v, 8);
      reinterpret_cast<uint2*>(dst)[2] = PACK8(v, 16);
      reinterpret_cast<uint2*>(dst)[3] = PACK8(v, 24);
    }
  } else if (!isf1) {
    const int u0 = t - 128;
#pragma unroll
    for (int k = 0; k < 8; ++k) {
      const int idx = u0 + 128 * k;
      const int c = idx >> 5, r = idx & 31, y = r >> 3, x = r & 7;
      s1[c][y][x] = 0.25f * (s0[c][2 * y][2 * x] + s0[c][2 * y][2 * x + 1] +
                             s0[c][2 * y + 1][2 * x] + s0[c][2 * y + 1][2 * x + 1]);
    }
  }
  if (isf1) return;
  __syncthreads();

  // phase 3: write level1 (fp8); compute level2
  if (t < 32) {
    const int y = t >> 3, x = t & 7;
    float v[32];
#pragma unroll
    for (int e = 0; e < 32; ++e) v[e] = s1[e][y][x];
    char* dst = pyr + PL1 +
                ((size_t)b * (24 * 32) + (size_t)(y0 / 2 + y) * 32 + (x0 / 2 + x)) * C + c0;
    reinterpret_cast<uint2*>(dst)[0] = PACK8(v, 0);
    reinterpret_cast<uint2*>(dst)[1] = PACK8(v, 8);
    reinterpret_cast<uint2*>(dst)[2] = PACK8(v, 16);
    reinterpret_cast<uint2*>(dst)[3] = PACK8(v, 24);
  } else if (t >= 64 && t < 192) {
    const int u0 = t - 64;
#pragma unroll
    for (int k = 0; k < 2; ++k) {
      const int idx = u0 + 128 * k;
      const int c = idx >> 3, r = idx & 7, y = r >> 2, x = r & 3;
      s2[c][y][x] = 0.25f * (s1[c][2 * y][2 * x] + s1[c][2 * y][2 * x + 1] +
                             s1[c][2 * y + 1][2 * x] + s1[c][2 * y + 1][2 * x + 1]);
    }
  }
  __syncthreads();

  // phase 4: write level2; compute+write level3
  if (t < 8) {
    const int y = t >> 2, x = t & 3;
    float v[32];
#pragma unroll
    for (int e = 0; e < 32; ++e) v[e] = s2[e][y][x];
    char* dst = pyr + PL2 +
                ((size_t)b * (12 * 16) + (size_t)(y0 / 4 + y) * 16 + (x0 / 4 + x)) * C + c0;
    reinterpret_cast<uint2*>(dst)[0] = PACK8(v, 0);
    reinterpret_cast<uint2*>(dst)[1] = PACK8(v, 8);
    reinterpret_cast<uint2*>(dst)[2] = PACK8(v, 16);
    reinterpret_cast<uint2*>(dst)[3] = PACK8(v, 24);
  } else if (t >= 8 && t < 10) {
    const int x = t - 8;
    float v[32];
#pragma unroll
    for (int e = 0; e < 32; ++e)
      v[e] = 0.25f * (s2[e][0][2 * x] + s2[e][0][2 * x + 1] +
                      s2[e][1][2 * x] + s2[e][1][2 * x + 1]);
    char* dst = pyr + PL3 +
                ((size_t)b * (6 * 8) + (size_t)(y0 / 8) * 8 + (x0 / 8 + x)) * C + c0;
    reinterpret_cast<uint2*>(dst)[0] = PACK8(v, 0);
    reinterpret_cast<uint2*>(dst)[1] = PACK8(v, 8);
    reinterpret_cast<uint2*>(dst)[2] = PACK8(v, 16);
    reinterpret_cast<uint2*>(dst)[3] = PACK8(v, 24);
  }
}

// ---------------------------------------------------------------------------
// C: main sampler (R9 structure — best measured). One block per (b,pix),
// XCD-chunk-swizzled, 4 waves. 16 lanes per sample; lane owns 16 fp8
// channels (one uint4 per corner). Depth-2 sample pairing; (256,4) bound
// avoids the (256,8) scratch spill. This sits at the random-gather L2
// throughput wall (~46 us for 805 MB of 256B-granule reads).
// ---------------------------------------------------------------------------
template <int STAGED>
__global__ __launch_bounds__(256, 4) void k_sample(
    const _Float16* __restrict__ f1cl, const char* __restrict__ pyr,
    const float* __restrict__ coords, float* __restrict__ dstf,
    _Float16* __restrict__ dsth) {
  __shared__ uint4 s_off[128];
  __shared__ uint4 s_w[128];
  __shared__ float s_out[128 * 9];
  const int bid0 = blockIdx.x;
  const int bid  = (bid0 & 7) * 768 + (bid0 >> 3);  // XCD chunk swizzle
  const int b    = (bid >= P) ? 1 : 0;
  const int pix  = bid - b * P;
  const int t    = threadIdx.x;

  if (t < 128) {
    const int lvl = t >> 5, d = t & 31;
    const float cx = coords[(((size_t)(b * 2 + 0) * NLVL + lvl) * D1 + d) * P + pix];
    const float cy = coords[(((size_t)(b * 2 + 1) * NLVL + lvl) * D1 + d) * P + pix];
    const int Hi = H >> lvl, Wi = W >> lvl;
    const float sc = 1.0f / (float)(1 << lvl);
    const float xf = (cx + 0.5f) * sc - 0.5f;
    const float yf = (cy + 0.5f) * sc - 0.5f;
    const float x0f = floorf(xf), y0f = floorf(yf);
    const int x0 = (int)x0f, y0 = (int)y0f;
    const int x1 = x0 + 1, y1 = y0 + 1;
    const float fx = xf - x0f, fy = yf - y0f;
    const float vx0 = (x0 >= 0 && x0 < Wi) ? -WSC : 0.f;  // negated weights
    const float vx1 = (x1 >= 0 && x1 < Wi) ? -WSC : 0.f;
    const float vy0 = (y0 >= 0 && y0 < Hi) ? 1.f : 0.f;
    const float vy1 = (y1 >= 0 && y1 < Hi) ? 1.f : 0.f;
    const int x0c = min(max(x0, 0), Wi - 1), x1c = min(max(x1, 0), Wi - 1);
    const int y0c = min(max(y0, 0), Hi - 1), y1c = min(max(y1, 0), Hi - 1);
    h2 p00, p10, p01, p11;
    p00.x = p00.y = (_Float16)((1.f - fx) * (1.f - fy) * vx0 * vy0);
    p10.x = p10.y = (_Float16)(fx * (1.f - fy) * vx1 * vy0);
    p01.x = p01.y = (_Float16)((1.f - fx) * fy * vx0 * vy1);
    p11.x = p11.y = (_Float16)(fx * fy * vx1 * vy1);
    s_w[t] = make_uint4(h2u(p00), h2u(p10), h2u(p01), h2u(p11));
    // pyr-relative byte offsets, level+batch base folded in
    const unsigned npx = (unsigned)(Hi * Wi);
    const unsigned lbase =
        (unsigned)((lvl == 0) ? PL0 : (lvl == 1) ? PL1 : (lvl == 2) ? PL2 : PL3) +
        (unsigned)b * npx * C;
    s_off[t] = make_uint4(lbase + (unsigned)(y0c * Wi + x0c) * C,
                          lbase + (unsigned)(y0c * Wi + x1c) * C,
                          lbase + (unsigned)(y1c * Wi + x0c) * C,
                          lbase + (unsigned)(y1c * Wi + x1c) * C);
  }

  const int lane = t & 63;
  const int wave = t >> 6;
  const int q    = lane >> 4;   // quarter-wave = sample slot
  const int li   = lane & 15;   // lane within sample
  const unsigned chb = (unsigned)li * 16u;  // fp8 byte offset of lane's 16 ch

  // f1 fragment: 16 channels fp16 (32 B)
  h2 f1h[8];
  {
    const uint4* fp = reinterpret_cast<const uint4*>(
        reinterpret_cast<const char*>(f1cl) + ((size_t)b * P + pix) * (C * 2) + li * 32);
    const uint4 fa = fp[0], fb = fp[1];
    f1h[0] = u2h(fa.x); f1h[1] = u2h(fa.y); f1h[2] = u2h(fa.z); f1h[3] = u2h(fa.w);
    f1h[4] = u2h(fb.x); f1h[5] = u2h(fb.y); f1h[6] = u2h(fb.z); f1h[7] = u2h(fb.w);
  }

  __syncthreads();

#ifdef HAS_HW_FP8_DEC
#define DECFMA(v, wu)                                                          \
  {                                                                            \
    const h2 w = u2h(wu);                                                      \
    acc[0] += w * __builtin_amdgcn_cvt_scalef32_pk_f16_fp8((v).x, 1.0f, false);\
    acc[1] += w * __builtin_amdgcn_cvt_scalef32_pk_f16_fp8((v).x, 1.0f, true); \
    acc[2] += w * __builtin_amdgcn_cvt_scalef32_pk_f16_fp8((v).y, 1.0f, false);\
    acc[3] += w * __builtin_amdgcn_cvt_scalef32_pk_f16_fp8((v).y, 1.0f, true); \
    acc[4] += w * __builtin_amdgcn_cvt_scalef32_pk_f16_fp8((v).z, 1.0f, false);\
    acc[5] += w * __builtin_amdgcn_cvt_scalef32_pk_f16_fp8((v).z, 1.0f, true); \
    acc[6] += w * __builtin_amdgcn_cvt_scalef32_pk_f16_fp8((v).w, 1.0f, false);\
    acc[7] += w * __builtin_amdgcn_cvt_scalef32_pk_f16_fp8((v).w, 1.0f, true); \
  }
#else
#define DECFMA(v, wu)                                                          \
  {                                                                            \
    const h2 w = u2h(wu);                                                      \
    h2 lo, hi;                                                                 \
    fp8x4_to_h2x2((v).x, lo, hi); acc[0] += w * lo; acc[1] += w * hi;          \
    fp8x4_to_h2x2((v).y, lo, hi); acc[2] += w * lo; acc[3] += w * hi;          \
    fp8x4_to_h2x2((v).z, lo, hi); acc[4] += w * lo; acc[5] += w * hi;          \
    fp8x4_to_h2x2((v).w, lo, hi); acc[6] += w * lo; acc[7] += w * hi;          \
  }
#endif

#define REDUCE_STORE(sidx)                                                     \
  {                                                                            \
    const h2 s01 = habs2(acc[0]) + habs2(acc[1]);                              \
    const h2 s23 = habs2(acc[2]) + habs2(acc[3]);                              \
    const h2 s45 = habs2(acc[4]) + habs2(acc[5]);                              \
    const h2 s67 = habs2(acc[6]) + habs2(acc[7]);                              \
    const h2 s   = (s01 + s23) + (s45 + s67);                                  \
    float a = (float)s.x + (float)s.y;                                         \
    a += __shfl_xor(a, 1);                                                     \
    if ((li & 1) == 0) s_out[(sidx) * 9 + (li >> 1)] = a * (1.0f / 32.0f);     \
  }

#pragma unroll
  for (int ip = 0; ip < 4; ++ip) {
    const int sA = (2 * ip) * 16 + wave * 4 + q;
    const int sB = sA + 16;
    const uint4 oA = s_off[sA], wA = s_w[sA];
    const uint4 oB = s_off[sB], wB = s_w[sB];
    // issue all 8 corner loads (A then B) before any compute
    const uint4 a0 = *reinterpret_cast<const uint4*>(pyr + (oA.x + chb));
    const uint4 a1 = *reinterpret_cast<const uint4*>(pyr + (oA.y + chb));
    const uint4 a2 = *reinterpret_cast<const uint4*>(pyr + (oA.z + chb));
    const uint4 a3 = *reinterpret_cast<const uint4*>(pyr + (oA.w + chb));
    const uint4 b0 = *reinterpret_cast<const uint4*>(pyr + (oB.x + chb));
    const uint4 b1 = *reinterpret_cast<const uint4*>(pyr + (oB.y + chb));
    const uint4 b2 = *reinterpret_cast<const uint4*>(pyr + (oB.z + chb));
    const uint4 b3 = *reinterpret_cast<const uint4*>(pyr + (oB.w + chb));
    {
      h2 acc[8];
#pragma unroll
      for (int k = 0; k < 8; ++k) acc[k] = f1h[k];
      DECFMA(a0, wA.x) DECFMA(a1, wA.y) DECFMA(a2, wA.z) DECFMA(a3, wA.w)
      REDUCE_STORE(sA)
    }
    {
      h2 acc[8];
#pragma unroll
      for (int k = 0; k < 8; ++k) acc[k] = f1h[k];
      DECFMA(b0, wB.x) DECFMA(b1, wB.y) DECFMA(b2, wB.z) DECFMA(b3, wB.w)
      REDUCE_STORE(sB)
    }
  }

  __syncthreads();
  if (STAGED) {
    union { unsigned qq[2]; h2 hh[2]; } u;
#pragma unroll
    for (int j = 0; j < 2; ++j) {
      const int c0i = t * 4 + j * 2;
      const int c1i = c0i + 1;
      u.hh[j].x = (_Float16)s_out[((c0i >> 8) * 32 + (c0i & 31)) * 9 + ((c0i >> 5) & 7)];
      u.hh[j].y = (_Float16)s_out[((c1i >> 8) * 32 + (c1i & 31)) * 9 + ((c1i >> 5) & 7)];
    }
    *reinterpret_cast<uint2*>(dsth + ((size_t)b * P + pix) * CHO + t * 4) =
        make_uint2(u.qq[0], u.qq[1]);
  } else {
#pragma unroll
    for (int j = 0; j < 4; ++j) {
      const int ch = t * 4 + j;
      dstf[((size_t)b * CHO + ch) * P + pix] =
          s_out[((ch >> 8) * 32 + (ch & 31)) * 9 + ((ch >> 5) & 7)];
    }
  }
}

// ---------------------------------------------------------------------------
// D: transpose out_tmp fp16 [B][P][CHO] -> out f32 [B][CHO][P].
// ---------------------------------------------------------------------------
__global__ __launch_bounds__(256) void k_out_t(
    const _Float16* __restrict__ ot, float* __restrict__ out) {
  __shared__ float tile[32][33];
  const int b  = blockIdx.z;
  const int p0 = blockIdx.x * 32;
  const int c0 = blockIdx.y * 32;
  const int tx = threadIdx.x, ty = threadIdx.y;
#pragma unroll
  for (int i = 0; i < 32; i += 8)
    tile[ty + i][tx] = (float)ot[((size_t)b * P + p0 + ty + i) * CHO + c0 + tx];
  __syncthreads();
#pragma unroll
  for (int i = 0; i < 32; i += 8)
    out[((size_t)b * CHO + c0 + ty + i) * P + p0 + tx] = tile[tx][ty + i];
}

extern "C" void kernel_launch(void* const* d_in, const int* in_sizes, int n_in,
                              void* d_out, int out_size, void* d_ws, size_t ws_size,
                              hipStream_t stream) {
  const float* fmap1  = (const float*)d_in[0];
  const float* fmap2  = (const float*)d_in[1];
  const float* coords = (const float*)d_in[2];
  float* out = (float*)d_out;
  char* ws   = (char*)d_ws;

  k_prep<<<dim3(4, 6, 32), 256, 0, stream>>>(fmap1, fmap2, ws);

  const _Float16* f1cl = (const _Float16*)ws;
  const char* pyr = ws + F1_BYTES;
  if (ws_size >= WS_NEEDED) {
    _Float16* ot = (_Float16*)(ws + OT_OFF);
    k_sample<1><<<B2 * P, 256, 0, stream>>>(f1cl, pyr, coords, out, ot);
    k_out_t<<<dim3(96, 32, 2), dim3(32, 8), 0, stream>>>(ot, out);
  } else {
    k_sample<0><<<B2 * P, 256, 0, stream>>>(f1cl, pyr, coords, out, nullptr);
  }
}